// Round 2
// baseline (359.713 us; speedup 1.0000x reference)
//
#include <hip/hip_runtime.h>
#include <stdint.h>

typedef __bf16 bf16x8 __attribute__((ext_vector_type(8)));
typedef float floatx4 __attribute__((ext_vector_type(4)));
typedef uint32_t uint32x4 __attribute__((ext_vector_type(4)));

#define GRID_W   15
#define PAD_W    17
#define CELLS    221            // 13*17 padded cells
#define HEXDIM   64
#define NHEX     165
#define OUTC     64
#define KDIM     448
#define CWORDS   32             // uint32 words per cell (64 bf16)
#define SXWORDS  (CELLS * CWORDS)   // 7072 words = 28288 B per buffer
#define SPB      4              // samples pipelined per block
#define XF4      (NHEX * HEXDIM / 4)   // 2640 float4 per sample

// round-to-nearest-even fp32 -> bf16, packed pair
__device__ __forceinline__ uint32_t pack2bf(float a, float b) {
    union { float f; uint32_t u; } ua, ub;
    ua.f = a; ub.f = b;
    uint32_t ra = (ua.u + 0x7fffu + ((ua.u >> 16) & 1u)) >> 16;
    uint32_t rb = (ub.u + 0x7fffu + ((ub.u >> 16) & 1u)) >> 16;
    return ra | (rb << 16);
}

// ---- prep: W fp32 -> bf16 (64*448 = 28672 elems, 7168 float4s, 28 blocks) ----
__global__ void wprep_kernel(const float* __restrict__ W, uint32_t* __restrict__ Wbf) {
    int i = blockIdx.x * 256 + threadIdx.x;   // float4 index
    float4 v = ((const float4*)W)[i];
    uint2 p; p.x = pack2bf(v.x, v.y); p.y = pack2bf(v.z, v.w);
    ((uint2*)Wbf)[i] = p;
}

// Operand-swapped MFMA: A = W fragment (o rows), B = x fragment (hex cols).
// C tile is (o = row, hex = col) -> each lane holds 4 consecutive o's for one hex.
__device__ __forceinline__ floatx4 mfma16(uint32x4 a, uint32x4 b, floatx4 c) {
    return __builtin_amdgcn_mfma_f32_16x16x32_bf16(
        __builtin_bit_cast(bf16x8, a), __builtin_bit_cast(bf16x8, b), c, 0, 0, 0);
}

__global__ __launch_bounds__(512, 4)
void hexconv_kernel(const float* __restrict__ x,
                    const uint32_t* __restrict__ Wbf,
                    const float* __restrict__ bias,
                    float* __restrict__ out, int B)
{
    // double-buffered grid: 56,576 B -> 2 blocks/CU, 32 waves resident
    __shared__ __align__(16) uint32_t sx[2 * SXWORDS];

    const int tid  = threadIdx.x;
    const int wave = tid >> 6;
    const int lane = tid & 63;
    const int col  = lane & 15;   // o within tile (A-row) / hex within tile (B/C-col)
    const int kq   = lane >> 4;   // k-quad
    const int og   = wave & 1;    // o-pair: o-tiles og*2, og*2+1
    const int mg   = wave >> 1;   // m-group: m-tiles mg*3 + {0,1,2}

    const uint32_t* w0 = Wbf + (og * 32 + col) * (KDIM / 2) + kq * 4;
    const uint32_t* w1 = w0 + 16 * (KDIM / 2);

    // ---- staging LDS dest word-offsets (sample-invariant) ----
    int dstoff[6];
    #pragma unroll
    for (int j = 0; j < 6; ++j) {
        int i  = tid + j * 512;
        int ii = (i < XF4) ? i : 0;       // j==5 tail: only tid<80 real
        int n = ii >> 4, d = ii & 15;
        int y0 = n / GRID_W, x0 = n - y0 * GRID_W;
        int cell = (y0 + 1) * PAD_W + (x0 + 1);
        int pc   = (d >> 1) ^ (cell & 7); // swizzled 16B chunk
        dstoff[j] = cell * CWORDS + pc * 4 + (d & 1) * 2;
    }

    const int s0 = blockIdx.x * SPB;
    const float4* xs0 = (const float4*)x + (size_t)s0 * XF4;

    // ---- prologue: issue sample-0 loads, zero halos of BOTH buffers, write, barrier
    float4 pv[6];
    if (s0 < B) {
        #pragma unroll
        for (int j = 0; j < 5; ++j) pv[j] = xs0[tid + j * 512];
        if (tid < XF4 - 5 * 512) pv[5] = xs0[tid + 5 * 512];
    }
    if (tid < 56 * 8) {               // 56 halo cells x 8 chunks of 16B
        int c = tid >> 3, ch = tid & 7;
        int cell;
        if (c < 17)      cell = c;                        // top row 0
        else if (c < 34) cell = 12 * PAD_W + (c - 17);    // bottom row 12
        else if (c < 45) cell = (c - 33) * PAD_W;         // left col, rows 1..11
        else             cell = (c - 44) * PAD_W + 16;    // right col, rows 1..11
        uint32x4 z = {0u, 0u, 0u, 0u};
        *(uint32x4*)(sx + cell * CWORDS + ch * 4) = z;
        *(uint32x4*)(sx + SXWORDS + cell * CWORDS + ch * 4) = z;
    }
    if (s0 < B) {
        #pragma unroll
        for (int j = 0; j < 5; ++j) {
            uint2 p; p.x = pack2bf(pv[j].x, pv[j].y); p.y = pack2bf(pv[j].z, pv[j].w);
            *(uint2*)(sx + dstoff[j]) = p;
        }
        if (tid < XF4 - 5 * 512) {
            uint2 p; p.x = pack2bf(pv[5].x, pv[5].y); p.y = pack2bf(pv[5].z, pv[5].w);
            *(uint2*)(sx + dstoff[5]) = p;
        }
    }
    __syncthreads();

    const int off0[7] = {-17, -16, -1, 0, 1, 17, 18};
    const int off1[7] = {-18, -17, -1, 0, 1, 16, 17};

    // ---- main loop: SPB samples, stage(s+1) overlapped with compute(s) ----
    #pragma unroll
    for (int s = 0; s < SPB; ++s) {
        const bool sval = (s0 + s) < B;       // block-uniform
        const bool nval = (s + 1 < SPB) && ((s0 + s + 1) < B);

        // issue next-sample global loads FIRST (fly under compute)
        float4 sv[6];
        if (nval) {
            const float4* xsn = xs0 + (size_t)(s + 1) * XF4;
            #pragma unroll
            for (int j = 0; j < 5; ++j) sv[j] = xsn[tid + j * 512];
            if (tid < XF4 - 5 * 512) sv[5] = xsn[tid + 5 * 512];
        }

        if (sval) {
            const uint32_t* sb = sx + (s & 1) * SXWORDS;

            // per-m-tile neighbor bases (hoisted out of K-half loop)
            int base3[3]; int use3[3]; int valid3[3];
            #pragma unroll
            for (int mt3 = 0; mt3 < 3; ++mt3) {
                int mt = mg * 3 + mt3;
                int n  = mt * 16 + col;
                bool valid = (n < NHEX);
                int nn = valid ? n : 0;
                int y0 = nn / GRID_W, x0 = nn - y0 * GRID_W;
                base3[mt3]  = (y0 + 1) * PAD_W + (x0 + 1);
                use3[mt3]   = (y0 & 1);
                valid3[mt3] = valid;
            }

            floatx4 acc[3][2];
            #pragma unroll
            for (int m = 0; m < 3; ++m) {
                acc[m][0] = (floatx4){0.f, 0.f, 0.f, 0.f};
                acc[m][1] = (floatx4){0.f, 0.f, 0.f, 0.f};
            }

            #pragma unroll
            for (int half = 0; half < 2; ++half) {
                uint32x4 wf[2][7];
                #pragma unroll
                for (int ksl = 0; ksl < 7; ++ksl) {
                    wf[0][ksl] = *(const uint32x4*)(w0 + half * 112 + ksl * 16);
                    wf[1][ksl] = *(const uint32x4*)(w1 + half * 112 + ksl * 16);
                }
                #pragma unroll
                for (int mt3 = 0; mt3 < 3; ++mt3) {
                    const int mt = mg * 3 + mt3;
                    if (mt * 16 < NHEX) {    // skip fully-dead tile 11 (wave-uniform)
                        #pragma unroll
                        for (int ksl = 0; ksl < 7; ++ksl) {
                            const int ks = half * 7 + ksl;   // constexpr
                            const int j  = ks >> 1;          // neighbor 0..6
                            const int h  = ks & 1;           // dim-half
                            int c  = valid3[mt3] ? (base3[mt3] + (use3[mt3] ? off0[j] : off1[j]))
                                                 : 16;       // cell 16 = halo(0)
                            int ch = ((h * 4 + kq) ^ (c & 7));
                            uint32x4 bv = *(const uint32x4*)(sb + c * CWORDS + ch * 4);
                            acc[mt3][0] = mfma16(wf[0][ksl], bv, acc[mt3][0]);
                            acc[mt3][1] = mfma16(wf[1][ksl], bv, acc[mt3][1]);
                        }
                    }
                }
            }

            // ---- epilogue: lane holds 4 consecutive o's for one hex -> float4 stores
            float4 b40 = *(const float4*)(bias + og * 32 + kq * 4);
            float4 b41 = *(const float4*)(bias + og * 32 + 16 + kq * 4);
            float* outb = out + (size_t)(s0 + s) * NHEX * OUTC;
            #pragma unroll
            for (int mt3 = 0; mt3 < 3; ++mt3) {
                int n = (mg * 3 + mt3) * 16 + col;
                if (n < NHEX) {
                    float* po = outb + (size_t)n * OUTC + og * 32 + kq * 4;
                    float4 v0, v1;
                    v0.x = acc[mt3][0][0] + b40.x; v0.y = acc[mt3][0][1] + b40.y;
                    v0.z = acc[mt3][0][2] + b40.z; v0.w = acc[mt3][0][3] + b40.w;
                    v1.x = acc[mt3][1][0] + b41.x; v1.y = acc[mt3][1][1] + b41.y;
                    v1.z = acc[mt3][1][2] + b41.z; v1.w = acc[mt3][1][3] + b41.w;
                    *(float4*)po        = v0;
                    *(float4*)(po + 16) = v1;
                }
            }
        }

        // ---- write next sample into the other buffer, single barrier per sample
        if (s + 1 < SPB) {
            if (nval) {
                uint32_t* db = sx + ((s + 1) & 1) * SXWORDS;
                #pragma unroll
                for (int j = 0; j < 5; ++j) {
                    uint2 p; p.x = pack2bf(sv[j].x, sv[j].y); p.y = pack2bf(sv[j].z, sv[j].w);
                    *(uint2*)(db + dstoff[j]) = p;
                }
                if (tid < XF4 - 5 * 512) {
                    uint2 p; p.x = pack2bf(sv[5].x, sv[5].y); p.y = pack2bf(sv[5].z, sv[5].w);
                    *(uint2*)(db + dstoff[5]) = p;
                }
            }
            __syncthreads();
        }
    }
}

extern "C" void kernel_launch(void* const* d_in, const int* in_sizes, int n_in,
                              void* d_out, int out_size, void* d_ws, size_t ws_size,
                              hipStream_t stream) {
    const float* x    = (const float*)d_in[0];
    const float* W    = (const float*)d_in[1];
    const float* bias = (const float*)d_in[2];
    float* out        = (float*)d_out;
    uint32_t* Wbf     = (uint32_t*)d_ws;      // 57,344 B of bf16 W

    wprep_kernel<<<28, 256, 0, stream>>>(W, Wbf);

    int B = in_sizes[0] / (NHEX * HEXDIM);
    int nb = (B + SPB - 1) / SPB;
    hexconv_kernel<<<nb, 512, 0, stream>>>(x, Wbf, bias, out, B);
}

// Round 3
// 270.536 us; speedup vs baseline: 1.3296x; 1.3296x over previous
//
#include <hip/hip_runtime.h>
#include <stdint.h>

typedef __bf16 bf16x8 __attribute__((ext_vector_type(8)));
typedef float floatx4 __attribute__((ext_vector_type(4)));
typedef uint32_t uint32x4 __attribute__((ext_vector_type(4)));

#define GRID_W   15
#define PAD_W    17
#define CELLS    221            // 13*17 padded cells
#define HEXDIM   64
#define NHEX     165
#define OUTC     64
#define KDIM     448
#define CWORDS   32             // uint32 words per cell (64 bf16)
#define SXWORDS  (CELLS * CWORDS)   // 7072 words = 28288 B per buffer
#define SPB      4              // samples pipelined per block
#define XF4      (NHEX * HEXDIM / 4)   // 2640 float4 per sample

// round-to-nearest-even fp32 -> bf16, packed pair
__device__ __forceinline__ uint32_t pack2bf(float a, float b) {
    union { float f; uint32_t u; } ua, ub;
    ua.f = a; ub.f = b;
    uint32_t ra = (ua.u + 0x7fffu + ((ua.u >> 16) & 1u)) >> 16;
    uint32_t rb = (ub.u + 0x7fffu + ((ub.u >> 16) & 1u)) >> 16;
    return ra | (rb << 16);
}

// ---- prep: W fp32 -> bf16 (64*448 = 28672 elems, 7168 float4s, 28 blocks) ----
__global__ void wprep_kernel(const float* __restrict__ W, uint32_t* __restrict__ Wbf) {
    int i = blockIdx.x * 256 + threadIdx.x;   // float4 index
    float4 v = ((const float4*)W)[i];
    uint2 p; p.x = pack2bf(v.x, v.y); p.y = pack2bf(v.z, v.w);
    ((uint2*)Wbf)[i] = p;
}

// Operand-swapped MFMA: A = W fragment (o rows), B = x fragment (hex cols).
// C tile is (o = row, hex = col) -> each lane holds 4 consecutive o's for one hex.
__device__ __forceinline__ floatx4 mfma16(uint32x4 a, uint32x4 b, floatx4 c) {
    return __builtin_amdgcn_mfma_f32_16x16x32_bf16(
        __builtin_bit_cast(bf16x8, a), __builtin_bit_cast(bf16x8, b), c, 0, 0, 0);
}

// One K-half (7 k-slices), ksl-outer / m-tile-inner: only ONE wf pair (8 VGPRs)
// live at a time instead of wf[2][7] (56) -- this is what keeps sv[] from spilling.
template<int HALF>
__device__ __forceinline__ void compute_half(const uint32_t* __restrict__ sb,
                                             const uint32_t* __restrict__ w0,
                                             const uint32_t* __restrict__ w1,
                                             const int* base3, const int* use3,
                                             const int* valid3, int kq, int mg,
                                             floatx4 acc[3][2])
{
    const int off0[7] = {-17, -16, -1, 0, 1, 17, 18};
    const int off1[7] = {-18, -17, -1, 0, 1, 16, 17};
    #pragma unroll
    for (int ksl = 0; ksl < 7; ++ksl) {
        uint32x4 wfa = *(const uint32x4*)(w0 + HALF * 112 + ksl * 16); // L2-resident
        uint32x4 wfb = *(const uint32x4*)(w1 + HALF * 112 + ksl * 16);
        const int ks = HALF * 7 + ksl;   // constexpr
        const int j  = ks >> 1;          // neighbor 0..6
        const int h  = ks & 1;           // dim-half of neighbor
        #pragma unroll
        for (int mt3 = 0; mt3 < 3; ++mt3) {
            if ((mg * 3 + mt3) * 16 < NHEX) {   // wave-uniform; skips dead tile 11
                int c  = valid3[mt3] ? (base3[mt3] + (use3[mt3] ? off0[j] : off1[j]))
                                     : 16;      // cell 16 = halo(0)
                int ch = ((h * 4 + kq) ^ (c & 7));
                uint32x4 bv = *(const uint32x4*)(sb + c * CWORDS + ch * 4); // ds_read_b128
                acc[mt3][0] = mfma16(wfa, bv, acc[mt3][0]);
                acc[mt3][1] = mfma16(wfb, bv, acc[mt3][1]);
            }
        }
    }
}

__global__ __launch_bounds__(512, 4)
void hexconv_kernel(const float* __restrict__ x,
                    const uint32_t* __restrict__ Wbf,
                    const float* __restrict__ bias,
                    float* __restrict__ out, int B)
{
    // double-buffered grid: 56,576 B -> 2 blocks/CU, 32 waves resident
    __shared__ __align__(16) uint32_t sx[2 * SXWORDS];

    const int tid  = threadIdx.x;
    const int wave = tid >> 6;
    const int lane = tid & 63;
    const int col  = lane & 15;   // o within tile (A-row) / hex within tile (B/C-col)
    const int kq   = lane >> 4;   // k-quad
    const int og   = wave & 1;    // o-pair: o-tiles og*2, og*2+1
    const int mg   = wave >> 1;   // m-group: m-tiles mg*3 + {0,1,2}

    const uint32_t* w0 = Wbf + (og * 32 + col) * (KDIM / 2) + kq * 4;
    const uint32_t* w1 = w0 + 16 * (KDIM / 2);

    // ---- staging LDS dest word-offsets (sample-invariant) ----
    int dstoff[6];
    #pragma unroll
    for (int j = 0; j < 6; ++j) {
        int i  = tid + j * 512;
        int ii = (i < XF4) ? i : 0;       // j==5 tail: only tid<80 real
        int n = ii >> 4, d = ii & 15;
        int y0 = n / GRID_W, x0 = n - y0 * GRID_W;
        int cell = (y0 + 1) * PAD_W + (x0 + 1);
        int pc   = (d >> 1) ^ (cell & 7); // swizzled 16B chunk
        dstoff[j] = cell * CWORDS + pc * 4 + (d & 1) * 2;
    }

    const int s0 = blockIdx.x * SPB;
    const float4* xs0 = (const float4*)x + (size_t)s0 * XF4;

    // ---- prologue: load sample 0, zero halos of BOTH buffers, write, barrier ----
    {
        float4 pv[6];
        if (s0 < B) {
            #pragma unroll
            for (int j = 0; j < 5; ++j) pv[j] = xs0[tid + j * 512];
            if (tid < XF4 - 5 * 512) pv[5] = xs0[tid + 5 * 512];
        }
        if (tid < 56 * 8) {               // 56 halo cells x 8 chunks of 16B
            int c = tid >> 3, ch = tid & 7;
            int cell;
            if (c < 17)      cell = c;                        // top row 0
            else if (c < 34) cell = 12 * PAD_W + (c - 17);    // bottom row 12
            else if (c < 45) cell = (c - 33) * PAD_W;         // left col, rows 1..11
            else             cell = (c - 44) * PAD_W + 16;    // right col, rows 1..11
            uint32x4 z = {0u, 0u, 0u, 0u};
            *(uint32x4*)(sx + cell * CWORDS + ch * 4) = z;
            *(uint32x4*)(sx + SXWORDS + cell * CWORDS + ch * 4) = z;
        }
        if (s0 < B) {
            #pragma unroll
            for (int j = 0; j < 5; ++j) {
                uint2 p; p.x = pack2bf(pv[j].x, pv[j].y); p.y = pack2bf(pv[j].z, pv[j].w);
                *(uint2*)(sx + dstoff[j]) = p;
            }
            if (tid < XF4 - 5 * 512) {
                uint2 p; p.x = pack2bf(pv[5].x, pv[5].y); p.y = pack2bf(pv[5].z, pv[5].w);
                *(uint2*)(sx + dstoff[5]) = p;
            }
        }
    }
    __syncthreads();

    // ---- main loop: SPB samples; stage(s+1) loads issued MID-compute(s) ----
    #pragma unroll 1
    for (int s = 0; s < SPB; ++s) {
        const int  gs   = s0 + s;
        const bool sval = gs < B;                         // block-uniform
        const bool nval = (s + 1 < SPB) && (gs + 1 < B);  // block-uniform
        const uint32_t* sb = sx + (s & 1) * SXWORDS;

        int base3[3], use3[3], valid3[3];
        floatx4 acc[3][2];
        #pragma unroll
        for (int m = 0; m < 3; ++m) {
            acc[m][0] = (floatx4){0.f, 0.f, 0.f, 0.f};
            acc[m][1] = (floatx4){0.f, 0.f, 0.f, 0.f};
        }

        if (sval) {
            #pragma unroll
            for (int mt3 = 0; mt3 < 3; ++mt3) {
                int mt = mg * 3 + mt3;
                int n  = mt * 16 + col;
                bool valid = (n < NHEX);
                int nn = valid ? n : 0;
                int y0 = nn / GRID_W, x0 = nn - y0 * GRID_W;
                base3[mt3]  = (y0 + 1) * PAD_W + (x0 + 1);
                use3[mt3]   = (y0 & 1);
                valid3[mt3] = valid;
            }
            compute_half<0>(sb, w0, w1, base3, use3, valid3, kq, mg, acc);
        }

        // issue next-sample loads BETWEEN halves: half-0 wf waits never see them,
        // half-1's 42 MFMAs hide their HBM latency. sched_barrier(0) pins placement.
        float4 sv[6];
        if (nval) {
            __builtin_amdgcn_sched_barrier(0);
            const float4* xsn = xs0 + (size_t)(s + 1) * XF4;
            #pragma unroll
            for (int j = 0; j < 5; ++j) sv[j] = xsn[tid + j * 512];
            if (tid < XF4 - 5 * 512) sv[5] = xsn[tid + 5 * 512];
            __builtin_amdgcn_sched_barrier(0);
        }

        if (sval) compute_half<1>(sb, w0, w1, base3, use3, valid3, kq, mg, acc);

        // publish next sample, barrier, THEN epilogue (register-only) overlaps
        if (s + 1 < SPB) {
            if (nval) {
                uint32_t* db = sx + ((s + 1) & 1) * SXWORDS;
                #pragma unroll
                for (int j = 0; j < 5; ++j) {
                    uint2 p; p.x = pack2bf(sv[j].x, sv[j].y); p.y = pack2bf(sv[j].z, sv[j].w);
                    *(uint2*)(db + dstoff[j]) = p;
                }
                if (tid < XF4 - 5 * 512) {
                    uint2 p; p.x = pack2bf(sv[5].x, sv[5].y); p.y = pack2bf(sv[5].z, sv[5].w);
                    *(uint2*)(db + dstoff[5]) = p;
                }
            }
            __syncthreads();
        }

        if (sval) {
            float4 b40 = *(const float4*)(bias + og * 32 + kq * 4);
            float4 b41 = *(const float4*)(bias + og * 32 + 16 + kq * 4);
            float* outb = out + (size_t)gs * NHEX * OUTC;
            #pragma unroll
            for (int mt3 = 0; mt3 < 3; ++mt3) {
                int n = (mg * 3 + mt3) * 16 + col;
                if (n < NHEX) {
                    float* po = outb + (size_t)n * OUTC + og * 32 + kq * 4;
                    float4 v0, v1;
                    v0.x = acc[mt3][0][0] + b40.x; v0.y = acc[mt3][0][1] + b40.y;
                    v0.z = acc[mt3][0][2] + b40.z; v0.w = acc[mt3][0][3] + b40.w;
                    v1.x = acc[mt3][1][0] + b41.x; v1.y = acc[mt3][1][1] + b41.y;
                    v1.z = acc[mt3][1][2] + b41.z; v1.w = acc[mt3][1][3] + b41.w;
                    *(float4*)po        = v0;   // o = og*32 + kq*4 .. +3
                    *(float4*)(po + 16) = v1;   // o = og*32 + 16 + kq*4 .. +3
                }
            }
        }
    }
}

extern "C" void kernel_launch(void* const* d_in, const int* in_sizes, int n_in,
                              void* d_out, int out_size, void* d_ws, size_t ws_size,
                              hipStream_t stream) {
    const float* x    = (const float*)d_in[0];
    const float* W    = (const float*)d_in[1];
    const float* bias = (const float*)d_in[2];
    float* out        = (float*)d_out;
    uint32_t* Wbf     = (uint32_t*)d_ws;      // 57,344 B of bf16 W

    wprep_kernel<<<28, 256, 0, stream>>>(W, Wbf);

    int B = in_sizes[0] / (NHEX * HEXDIM);
    int nb = (B + SPB - 1) / SPB;
    hexconv_kernel<<<nb, 512, 0, stream>>>(x, Wbf, bias, out, B);
}

// Round 7
// 210.635 us; speedup vs baseline: 1.7078x; 1.2844x over previous
//
#include <hip/hip_runtime.h>
#include <stdint.h>

typedef __bf16 bf16x8 __attribute__((ext_vector_type(8)));
typedef float floatx4 __attribute__((ext_vector_type(4)));
typedef uint32_t uint32x4 __attribute__((ext_vector_type(4)));

#define GRID_W   15
#define PAD_W    17
#define CELLS    221            // 13*17 padded cells
#define HEXDIM   64
#define NHEX     165
#define OUTC     64
#define KDIM     448
#define CWORDS   32             // uint32 words per cell (64 bf16)
#define SXWORDS  (CELLS * CWORDS)   // 7072 words = 28288 B per buffer
#define SPB      4              // samples pipelined per block
#define XF4      (NHEX * HEXDIM / 4)   // 2640 float4 per sample

// round-to-nearest-even fp32 -> bf16, packed pair
__device__ __forceinline__ uint32_t pack2bf(float a, float b) {
    union { float f; uint32_t u; } ua, ub;
    ua.f = a; ub.f = b;
    uint32_t ra = (ua.u + 0x7fffu + ((ua.u >> 16) & 1u)) >> 16;
    uint32_t rb = (ub.u + 0x7fffu + ((ub.u >> 16) & 1u)) >> 16;
    return ra | (rb << 16);
}

// ---- prep: W fp32 -> bf16 (64*448 = 28672 elems, 7168 float4s, 28 blocks) ----
__global__ void wprep_kernel(const float* __restrict__ W, uint32_t* __restrict__ Wbf) {
    int i = blockIdx.x * 256 + threadIdx.x;   // float4 index
    float4 v = ((const float4*)W)[i];
    uint2 p; p.x = pack2bf(v.x, v.y); p.y = pack2bf(v.z, v.w);
    ((uint2*)Wbf)[i] = p;
}

// Operand-swapped MFMA: A = W fragment (o rows), B = x fragment (hex cols).
// C tile is (o = row, hex = col) -> each lane holds 4 consecutive o's for one hex.
__device__ __forceinline__ floatx4 mfma16(uint32x4 a, uint32x4 b, floatx4 c) {
    return __builtin_amdgcn_mfma_f32_16x16x32_bf16(
        __builtin_bit_cast(bf16x8, a), __builtin_bit_cast(bf16x8, b), c, 0, 0, 0);
}

// One K-half (7 k-slices), ksl-outer / m-tile-inner: only ONE wf pair (8 VGPRs)
// live at a time instead of wf[2][7] (56) -- keeps the staged sv[] from spilling.
template<int HALF>
__device__ __forceinline__ void compute_half(const uint32_t* __restrict__ sb,
                                             const uint32_t* __restrict__ w0,
                                             const uint32_t* __restrict__ w1,
                                             const int* base3, const int* use3,
                                             const int* valid3, int kq, int mg,
                                             floatx4 acc[3][2])
{
    const int off0[7] = {-17, -16, -1, 0, 1, 17, 18};
    const int off1[7] = {-18, -17, -1, 0, 1, 16, 17};
    #pragma unroll
    for (int ksl = 0; ksl < 7; ++ksl) {
        uint32x4 wfa = *(const uint32x4*)(w0 + HALF * 112 + ksl * 16); // L2-resident
        uint32x4 wfb = *(const uint32x4*)(w1 + HALF * 112 + ksl * 16);
        const int ks = HALF * 7 + ksl;   // constexpr
        const int j  = ks >> 1;          // neighbor 0..6
        const int h  = ks & 1;           // dim-half of neighbor
        #pragma unroll
        for (int mt3 = 0; mt3 < 3; ++mt3) {
            if ((mg * 3 + mt3) * 16 < NHEX) {   // wave-uniform; skips dead tile 11
                int c  = valid3[mt3] ? (base3[mt3] + (use3[mt3] ? off0[j] : off1[j]))
                                     : 16;      // cell 16 = halo(0)
                int ch = ((h * 4 + kq) ^ (c & 7));
                uint32x4 bv = *(const uint32x4*)(sb + c * CWORDS + ch * 4); // ds_read_b128
                acc[mt3][0] = mfma16(wfa, bv, acc[mt3][0]);
                acc[mt3][1] = mfma16(wfb, bv, acc[mt3][1]);
            }
        }
    }
}

// launch_bounds(512, 2): empirically arg=4 capped VGPR at 64 (VGPR_Count=64 in
// rocprof r1-r3) and forced ~95MB of scratch spill of the staged sample.
// LDS (56.6KB) limits residency to 2 blocks/CU regardless, so demanding only
// 2 units here raises the VGPR cap to ~128 at zero occupancy cost.
__global__ __launch_bounds__(512, 2)
void hexconv_kernel(const float* __restrict__ x,
                    const uint32_t* __restrict__ Wbf,
                    const float* __restrict__ bias,
                    float* __restrict__ out, int B)
{
    // double-buffered grid: 56,576 B -> 2 blocks/CU, 16 waves resident
    __shared__ __align__(16) uint32_t sx[2 * SXWORDS];

    const int tid  = threadIdx.x;
    const int wave = tid >> 6;
    const int lane = tid & 63;
    const int col  = lane & 15;   // o within tile (A-row) / hex within tile (B/C-col)
    const int kq   = lane >> 4;   // k-quad
    const int og   = wave & 1;    // o-pair: o-tiles og*2, og*2+1
    const int mg   = wave >> 1;   // m-group: m-tiles mg*3 + {0,1,2}

    const uint32_t* w0 = Wbf + (og * 32 + col) * (KDIM / 2) + kq * 4;
    const uint32_t* w1 = w0 + 16 * (KDIM / 2);

    // ---- staging LDS dest word-offsets (sample-invariant) ----
    int dstoff[6];
    #pragma unroll
    for (int j = 0; j < 6; ++j) {
        int i  = tid + j * 512;
        int ii = (i < XF4) ? i : 0;       // j==5 tail: only tid<80 real
        int n = ii >> 4, d = ii & 15;
        int y0 = n / GRID_W, x0 = n - y0 * GRID_W;
        int cell = (y0 + 1) * PAD_W + (x0 + 1);
        int pc   = (d >> 1) ^ (cell & 7); // swizzled 16B chunk
        dstoff[j] = cell * CWORDS + pc * 4 + (d & 1) * 2;
    }

    const int s0 = blockIdx.x * SPB;
    const float4* xs0 = (const float4*)x + (size_t)s0 * XF4;

    // ---- prologue: load sample 0, zero halos of BOTH buffers, write, barrier ----
    {
        float4 pv[6];
        if (s0 < B) {
            #pragma unroll
            for (int j = 0; j < 5; ++j) pv[j] = xs0[tid + j * 512];
            if (tid < XF4 - 5 * 512) pv[5] = xs0[tid + 5 * 512];
        }
        if (tid < 56 * 8) {               // 56 halo cells x 8 chunks of 16B
            int c = tid >> 3, ch = tid & 7;
            int cell;
            if (c < 17)      cell = c;                        // top row 0
            else if (c < 34) cell = 12 * PAD_W + (c - 17);    // bottom row 12
            else if (c < 45) cell = (c - 33) * PAD_W;         // left col, rows 1..11
            else             cell = (c - 44) * PAD_W + 16;    // right col, rows 1..11
            uint32x4 z = {0u, 0u, 0u, 0u};
            *(uint32x4*)(sx + cell * CWORDS + ch * 4) = z;
            *(uint32x4*)(sx + SXWORDS + cell * CWORDS + ch * 4) = z;
        }
        if (s0 < B) {
            #pragma unroll
            for (int j = 0; j < 5; ++j) {
                uint2 p; p.x = pack2bf(pv[j].x, pv[j].y); p.y = pack2bf(pv[j].z, pv[j].w);
                *(uint2*)(sx + dstoff[j]) = p;
            }
            if (tid < XF4 - 5 * 512) {
                uint2 p; p.x = pack2bf(pv[5].x, pv[5].y); p.y = pack2bf(pv[5].z, pv[5].w);
                *(uint2*)(sx + dstoff[5]) = p;
            }
        }
    }
    __syncthreads();

    // ---- main loop: SPB samples; stage(s+1) loads issued MID-compute(s) ----
    #pragma unroll 1
    for (int s = 0; s < SPB; ++s) {
        const int  gs   = s0 + s;
        const bool sval = gs < B;                         // block-uniform
        const bool nval = (s + 1 < SPB) && (gs + 1 < B);  // block-uniform
        const uint32_t* sb = sx + (s & 1) * SXWORDS;

        int base3[3], use3[3], valid3[3];
        floatx4 acc[3][2];
        #pragma unroll
        for (int m = 0; m < 3; ++m) {
            acc[m][0] = (floatx4){0.f, 0.f, 0.f, 0.f};
            acc[m][1] = (floatx4){0.f, 0.f, 0.f, 0.f};
        }

        if (sval) {
            #pragma unroll
            for (int mt3 = 0; mt3 < 3; ++mt3) {
                int mt = mg * 3 + mt3;
                int n  = mt * 16 + col;
                bool valid = (n < NHEX);
                int nn = valid ? n : 0;
                int y0 = nn / GRID_W, x0 = nn - y0 * GRID_W;
                base3[mt3]  = (y0 + 1) * PAD_W + (x0 + 1);
                use3[mt3]   = (y0 & 1);
                valid3[mt3] = valid;
            }
            compute_half<0>(sb, w0, w1, base3, use3, valid3, kq, mg, acc);
        }

        // issue next-sample loads BETWEEN halves: half-0 wf waits never see them,
        // half-1's 42 MFMAs hide their HBM latency. sched_barrier(0) pins placement.
        float4 sv[6];
        if (nval) {
            __builtin_amdgcn_sched_barrier(0);
            const float4* xsn = xs0 + (size_t)(s + 1) * XF4;
            #pragma unroll
            for (int j = 0; j < 5; ++j) sv[j] = xsn[tid + j * 512];
            if (tid < XF4 - 5 * 512) sv[5] = xsn[tid + 5 * 512];
            __builtin_amdgcn_sched_barrier(0);
        }

        if (sval) compute_half<1>(sb, w0, w1, base3, use3, valid3, kq, mg, acc);

        // publish next sample, barrier, THEN epilogue (register-only) overlaps
        if (s + 1 < SPB) {
            if (nval) {
                uint32_t* db = sx + ((s + 1) & 1) * SXWORDS;
                #pragma unroll
                for (int j = 0; j < 5; ++j) {
                    uint2 p; p.x = pack2bf(sv[j].x, sv[j].y); p.y = pack2bf(sv[j].z, sv[j].w);
                    *(uint2*)(db + dstoff[j]) = p;
                }
                if (tid < XF4 - 5 * 512) {
                    uint2 p; p.x = pack2bf(sv[5].x, sv[5].y); p.y = pack2bf(sv[5].z, sv[5].w);
                    *(uint2*)(db + dstoff[5]) = p;
                }
            }
            __syncthreads();
        }

        if (sval) {
            float4 b40 = *(const float4*)(bias + og * 32 + kq * 4);
            float4 b41 = *(const float4*)(bias + og * 32 + 16 + kq * 4);
            float* outb = out + (size_t)gs * NHEX * OUTC;
            #pragma unroll
            for (int mt3 = 0; mt3 < 3; ++mt3) {
                int n = (mg * 3 + mt3) * 16 + col;
                if (n < NHEX) {
                    float* po = outb + (size_t)n * OUTC + og * 32 + kq * 4;
                    float4 v0, v1;
                    v0.x = acc[mt3][0][0] + b40.x; v0.y = acc[mt3][0][1] + b40.y;
                    v0.z = acc[mt3][0][2] + b40.z; v0.w = acc[mt3][0][3] + b40.w;
                    v1.x = acc[mt3][1][0] + b41.x; v1.y = acc[mt3][1][1] + b41.y;
                    v1.z = acc[mt3][1][2] + b41.z; v1.w = acc[mt3][1][3] + b41.w;
                    *(float4*)po        = v0;   // o = og*32 + kq*4 .. +3
                    *(float4*)(po + 16) = v1;   // o = og*32 + 16 + kq*4 .. +3
                }
            }
        }
    }
}

extern "C" void kernel_launch(void* const* d_in, const int* in_sizes, int n_in,
                              void* d_out, int out_size, void* d_ws, size_t ws_size,
                              hipStream_t stream) {
    const float* x    = (const float*)d_in[0];
    const float* W    = (const float*)d_in[1];
    const float* bias = (const float*)d_in[2];
    float* out        = (float*)d_out;
    uint32_t* Wbf     = (uint32_t*)d_ws;      // 57,344 B of bf16 W

    wprep_kernel<<<28, 256, 0, stream>>>(W, Wbf);

    int B = in_sizes[0] / (NHEX * HEXDIM);
    int nb = (B + SPB - 1) / SPB;
    hexconv_kernel<<<nb, 512, 0, stream>>>(x, Wbf, bias, out, B);
}

// Round 9
// 202.959 us; speedup vs baseline: 1.7723x; 1.0378x over previous
//
#include <hip/hip_runtime.h>
#include <stdint.h>

typedef __bf16 bf16x8 __attribute__((ext_vector_type(8)));
typedef float floatx4 __attribute__((ext_vector_type(4)));
typedef uint32_t uint32x4 __attribute__((ext_vector_type(4)));

#define GRID_W   15
#define PAD_W    17
#define CELLS    221            // 13*17 padded cells
#define HEXDIM   64
#define NHEX     165
#define OUTC     64
#define KDIM     448
#define CSTRIDE  20             // words per cell per half-buffer (16 data + 4 pad)
                                // pad=4 makes ds_read_b128 bank-OPTIMAL (8 acc/bank)
#define HBWORDS  (CELLS * CSTRIDE)  // 4420 words = 17,680 B per half-buffer
#define SPB      2              // samples per block
#define NUNITS   (2 * SPB)      // units = (sample, dim-half)
#define HF4      (NHEX * 8)     // 1320 float4 per half-sample

// round-to-nearest-even fp32 -> bf16, packed pair
__device__ __forceinline__ uint32_t pack2bf(float a, float b) {
    union { float f; uint32_t u; } ua, ub;
    ua.f = a; ub.f = b;
    uint32_t ra = (ua.u + 0x7fffu + ((ua.u >> 16) & 1u)) >> 16;
    uint32_t rb = (ub.u + 0x7fffu + ((ub.u >> 16) & 1u)) >> 16;
    return ra | (rb << 16);
}

// ---- prep: W fp32 -> bf16, K reordered h-major ----
// Wbf[o][word r]: r = H*112 + j*16 + w  holds dims {H*32+2w, H*32+2w+1} of neighbor j.
// K-permutation is legal (dot product); x-side fragment picks match below.
__global__ void wprep_kernel(const float* __restrict__ W, uint32_t* __restrict__ Wbf) {
    int o = blockIdx.x;              // 64 blocks
    int r = threadIdx.x;             // 256 threads, top 32 idle
    if (r < 224) {
        int H = r / 112, rr = r - H * 112;
        int j = rr >> 4, w = rr & 15;
        const float* src = W + o * KDIM + j * 64 + H * 32 + w * 2;
        Wbf[o * 224 + r] = pack2bf(src[0], src[1]);
    }
}

// Operand-swapped MFMA: A = W fragment (o rows), B = x fragment (hex cols).
// C tile is (o = row, hex = col) -> each lane holds 4 consecutive o's for one hex.
__device__ __forceinline__ floatx4 mfma16(uint32x4 a, uint32x4 b, floatx4 c) {
    return __builtin_amdgcn_mfma_f32_16x16x32_bf16(
        __builtin_bit_cast(bf16x8, a), __builtin_bit_cast(bf16x8, b), c, 0, 0, 0);
}

// launch_bounds(512, 2): empirical (r1-r7): for 512-thr blocks the 2nd arg acts
// as blocks/CU -> arg 4 capped VGPR at 64 (spilled), arg 2 caps at 128 (r7:
// VGPR=112, zero spill). Keep 2 = safe; if allocator lands <=85, HW can still
// co-schedule 3 blocks (launch_bounds is a minimum, not a limit).
__global__ __launch_bounds__(512, 2)
void hexconv_kernel(const float* __restrict__ x,
                    const uint32_t* __restrict__ Wbf,
                    const float* __restrict__ bias,
                    float* __restrict__ out, int B)
{
    // rolling half-buffers: 2 x 17,680 B = 35,360 B
    __shared__ __align__(16) uint32_t sx[2 * HBWORDS];

    const int tid  = threadIdx.x;
    const int wave = tid >> 6;
    const int lane = tid & 63;
    const int col  = lane & 15;   // o within tile (A-row) / hex within tile (B/C-col)
    const int kq   = lane >> 4;   // k-quad
    const int og   = wave & 1;    // o-pair: o-tiles og*2, og*2+1
    const int mg   = wave >> 1;   // m-group: m-tiles mg*3 + {0,1,2}

    const uint32_t* w0 = Wbf + (og * 32 + col) * 224 + kq * 4;
    const uint32_t* w1 = w0 + 16 * 224;

    // ---- staging offsets: 3 float4 per thread per half (1320 = 2*512 + 296) ----
    // src float4 idx (in sample) = n*16 + H*8 + dh; dst word = cell*CSTRIDE + dh*2
    int soff[3], doff[3];
    #pragma unroll
    for (int j = 0; j < 3; ++j) {
        int i  = tid + j * 512;
        int ii = (i < HF4) ? i : 0;
        int n = ii >> 3, dh = ii & 7;
        int y0 = n / GRID_W, x0 = n - y0 * GRID_W;
        int cell = (y0 + 1) * PAD_W + (x0 + 1);
        soff[j] = n * 16 + dh;            // + H*8 at use
        doff[j] = cell * CSTRIDE + dh * 2;
    }
    const bool v2 = tid < (HF4 - 2 * 512);   // 296-thread tail for j=2

    // ---- neighbor bases per m-tile (sample-invariant, hoisted) ----
    const int off0[7] = {-17, -16, -1, 0, 1, 17, 18};
    const int off1[7] = {-18, -17, -1, 0, 1, 16, 17};
    int base3[3], use3[3], valid3[3];
    #pragma unroll
    for (int mt3 = 0; mt3 < 3; ++mt3) {
        int n = (mg * 3 + mt3) * 16 + col;
        bool valid = (n < NHEX);
        int nn = valid ? n : 0;
        int y0 = nn / GRID_W, x0 = nn - y0 * GRID_W;
        base3[mt3]  = (y0 + 1) * PAD_W + (x0 + 1);
        use3[mt3]   = (y0 & 1);
        valid3[mt3] = valid;
    }

    const int s0 = blockIdx.x * SPB;
    const float4* xb = (const float4*)(x + (size_t)s0 * NHEX * HEXDIM);

    // ---- prologue: stage unit 0 = (s0, H=0); zero halos of BOTH buffers ----
    {
        float4 pv0, pv1, pv2;
        if (s0 < B) {
            pv0 = xb[soff[0]];
            pv1 = xb[soff[1]];
            if (v2) pv2 = xb[soff[2]];
        }
        if (tid < 448) {     // 56 halo cells x 4 chunks x 2 buffers
            int t = tid; int buf = t >= 224; t -= buf * 224;
            int c = t >> 2, ch = t & 3;
            int cell;
            if (c < 17)      cell = c;                        // top row 0
            else if (c < 34) cell = 12 * PAD_W + (c - 17);    // bottom row 12
            else if (c < 45) cell = (c - 33) * PAD_W;         // left col, rows 1..11
            else             cell = (c - 44) * PAD_W + 16;    // right col, rows 1..11
            uint32x4 z = {0u, 0u, 0u, 0u};
            *(uint32x4*)(sx + buf * HBWORDS + cell * CSTRIDE + ch * 4) = z;
        }
        if (s0 < B) {
            uint2 p;
            p.x = pack2bf(pv0.x, pv0.y); p.y = pack2bf(pv0.z, pv0.w);
            *(uint2*)(sx + doff[0]) = p;
            p.x = pack2bf(pv1.x, pv1.y); p.y = pack2bf(pv1.z, pv1.w);
            *(uint2*)(sx + doff[1]) = p;
            if (v2) {
                p.x = pack2bf(pv2.x, pv2.y); p.y = pack2bf(pv2.z, pv2.w);
                *(uint2*)(sx + doff[2]) = p;
            }
        }
    }
    __syncthreads();

    // ---- main loop over units: compute(u) from buf[u&1], stage(u+1) into buf[(u+1)&1].
    // Safe: buf[(u+1)&1]'s last readers (unit u-1) passed the barrier ending iter u-1.
    floatx4 acc[3][2];
    #pragma unroll 1
    for (int u = 0; u < NUNITS; ++u) {
        const int s = u >> 1, H = u & 1;
        const bool uval = (s0 + s) < B;
        const bool nval = (u + 1 < NUNITS) && ((s0 + ((u + 1) >> 1)) < B);
        const uint32_t* sb = sx + H * HBWORDS;

        if (H == 0) {
            #pragma unroll
            for (int m = 0; m < 3; ++m) {
                acc[m][0] = (floatx4){0.f, 0.f, 0.f, 0.f};
                acc[m][1] = (floatx4){0.f, 0.f, 0.f, 0.f};
            }
        }

        // issue next-unit stage loads first (fly under compute)
        float4 sv0, sv1, sv2;
        if (nval) {
            const float4* xs = xb + (size_t)((u + 1) >> 1) * (NHEX * HEXDIM / 4);
            int hb = ((u + 1) & 1) * 8;
            sv0 = xs[soff[0] + hb];
            sv1 = xs[soff[1] + hb];
            if (v2) sv2 = xs[soff[2] + hb];
            __builtin_amdgcn_sched_barrier(0);
        }

        if (uval) {
            const int Hw = H * 112;
            #pragma unroll
            for (int j = 0; j < 7; ++j) {
                uint32x4 wfa = *(const uint32x4*)(w0 + Hw + j * 16);  // L2-resident
                uint32x4 wfb = *(const uint32x4*)(w1 + Hw + j * 16);
                #pragma unroll
                for (int mt3 = 0; mt3 < 3; ++mt3) {
                    if ((mg * 3 + mt3) * 16 < NHEX) {   // wave-uniform; skips dead tile 11
                        int c = valid3[mt3] ? (base3[mt3] + (use3[mt3] ? off0[j] : off1[j]))
                                            : 16;       // cell 16 = halo(0)
                        uint32x4 bv = *(const uint32x4*)(sb + c * CSTRIDE + kq * 4);
                        acc[mt3][0] = mfma16(wfa, bv, acc[mt3][0]);
                        acc[mt3][1] = mfma16(wfb, bv, acc[mt3][1]);
                    }
                }
            }
        }

        // publish next unit, one barrier per unit
        if (u + 1 < NUNITS) {
            if (nval) {
                uint32_t* db = sx + ((u + 1) & 1) * HBWORDS;
                uint2 p;
                p.x = pack2bf(sv0.x, sv0.y); p.y = pack2bf(sv0.z, sv0.w);
                *(uint2*)(db + doff[0]) = p;
                p.x = pack2bf(sv1.x, sv1.y); p.y = pack2bf(sv1.z, sv1.w);
                *(uint2*)(db + doff[1]) = p;
                if (v2) {
                    p.x = pack2bf(sv2.x, sv2.y); p.y = pack2bf(sv2.z, sv2.w);
                    *(uint2*)(db + doff[2]) = p;
                }
            }
            __syncthreads();
        }

        // epilogue after the barrier (register-only, overlaps next unit's stage)
        if (H == 1 && uval) {
            float4 b40 = *(const float4*)(bias + og * 32 + kq * 4);
            float4 b41 = *(const float4*)(bias + og * 32 + 16 + kq * 4);
            float* outb = out + (size_t)(s0 + s) * NHEX * OUTC;
            #pragma unroll
            for (int mt3 = 0; mt3 < 3; ++mt3) {
                int n = (mg * 3 + mt3) * 16 + col;
                if (n < NHEX) {
                    float* po = outb + (size_t)n * OUTC + og * 32 + kq * 4;
                    float4 o0, o1;
                    o0.x = acc[mt3][0][0] + b40.x; o0.y = acc[mt3][0][1] + b40.y;
                    o0.z = acc[mt3][0][2] + b40.z; o0.w = acc[mt3][0][3] + b40.w;
                    o1.x = acc[mt3][1][0] + b41.x; o1.y = acc[mt3][1][1] + b41.y;
                    o1.z = acc[mt3][1][2] + b41.z; o1.w = acc[mt3][1][3] + b41.w;
                    *(float4*)po        = o0;   // o = og*32 + kq*4 .. +3
                    *(float4*)(po + 16) = o1;   // o = og*32 + 16 + kq*4 .. +3
                }
            }
        }
    }
}

extern "C" void kernel_launch(void* const* d_in, const int* in_sizes, int n_in,
                              void* d_out, int out_size, void* d_ws, size_t ws_size,
                              hipStream_t stream) {
    const float* x    = (const float*)d_in[0];
    const float* W    = (const float*)d_in[1];
    const float* bias = (const float*)d_in[2];
    float* out        = (float*)d_out;
    uint32_t* Wbf     = (uint32_t*)d_ws;      // 57,344 B of bf16 W (h-major K order)

    wprep_kernel<<<64, 256, 0, stream>>>(W, Wbf);

    int B = in_sizes[0] / (NHEX * HEXDIM);
    int nb = (B + SPB - 1) / SPB;
    hexconv_kernel<<<nb, 512, 0, stream>>>(x, Wbf, bias, out, B);
}